// Round 9
// baseline (264.460 us; speedup 1.0000x reference)
//
#include <hip/hip_runtime.h>
#include <stdint.h>

#define B_ 4
#define D_ 256
#define N_ 4096
#define K_ 8192
#define Q_ (B_*N_)   // 16384 queries

#define KSPLIT_ 4            // K-split
#define KSLICE_ (K_/KSPLIT_) // 2048 codes per block
#define CHUNK_ 64            // codes per chunk (2 x 32-code MFMA sub-tiles)
#define NCHUNK_ (KSLICE_/CHUNK_) // 32 chunks
#define QTILE_ 256           // queries per block (8 waves x 32)

typedef __attribute__((ext_vector_type(8))) short bf16x8;
typedef __attribute__((ext_vector_type(16))) float f32x16;

__device__ __forceinline__ unsigned short f32_to_bf16(float f) {
  unsigned u = __float_as_uint(f);
  unsigned r = 0x7FFFu + ((u >> 16) & 1u);
  return (unsigned short)((u + r) >> 16);
}
__device__ __forceinline__ float bf16_to_f32(unsigned short h) {
  return __uint_as_float(((unsigned)h) << 16);
}

// async global->LDS, 16B per lane; LDS dest is wave-uniform base + lane*16
__device__ __forceinline__ void gl_lds16(const void* g, void* l) {
  __builtin_amdgcn_global_load_lds(
      (const __attribute__((address_space(1))) unsigned int*)g,
      (__attribute__((address_space(3))) unsigned int*)l, 16, 0, 0);
}

// Transpose x [B, D, N] -> xh/xl [Q=B*N, D] bf16 hi/lo split.
__global__ void prep_x_kernel(const float* __restrict__ x,
                              unsigned short* __restrict__ xh,
                              unsigned short* __restrict__ xl) {
  __shared__ float tile[32][33];
  int b = blockIdx.z;
  int d0 = blockIdx.y * 32;
  int n0 = blockIdx.x * 32;
  int tx = threadIdx.x, ty = threadIdx.y;
  const float* xp = x + ((size_t)b * D_ + d0) * N_ + n0;
#pragma unroll
  for (int i = 0; i < 4; ++i)
    tile[ty + 8 * i][tx] = xp[(size_t)(ty + 8 * i) * N_ + tx];
  __syncthreads();
#pragma unroll
  for (int i = 0; i < 4; ++i) {
    int nl = ty + 8 * i;
    float v = tile[tx][nl];
    unsigned short h = f32_to_bf16(v);
    unsigned short l = f32_to_bf16(v - bf16_to_f32(h));
    size_t q = (size_t)b * N_ + n0 + nl;
    xh[q * D_ + d0 + tx] = h;
    xl[q * D_ + d0 + tx] = l;
  }
}

// Split e [K, D] into bf16 hi/lo; compute 0.5*||e_k||^2; init keys.
__global__ void prep_e_kernel(const float* __restrict__ e,
                              unsigned short* __restrict__ eh,
                              unsigned short* __restrict__ el,
                              float* __restrict__ e2h,
                              unsigned long long* __restrict__ keys) {
  int k = blockIdx.x;
  int d = threadIdx.x;  // 256 threads
  if (d < 2) keys[(size_t)k * 2 + d] = ~0ull;  // Q_ = 2*K_
  float v = e[(size_t)k * D_ + d];
  unsigned short h = f32_to_bf16(v);
  unsigned short l = f32_to_bf16(v - bf16_to_f32(h));
  eh[(size_t)k * D_ + d] = h;
  el[(size_t)k * D_ + d] = l;
  float s = v * v;
#pragma unroll
  for (int off = 32; off > 0; off >>= 1) s += __shfl_down(s, off, 64);
  __shared__ float ws4[4];
  if ((threadIdx.x & 63) == 0) ws4[threadIdx.x >> 6] = s;
  __syncthreads();
  if (threadIdx.x == 0) e2h[k] = 0.5f * (ws4[0] + ws4[1] + ws4[2] + ws4[3]);
}

// Main R9: R7 frame (CHUNK=64, 8 waves x 32 q, 2/SIMD) with the two
// 32-code sub-tiles' MFMAs INTERLEAVED AT INSTRUCTION GRANULARITY.
// Theory (fits all of R0-R8): the triple acc=mfma(..,acc) x3 is a
// distance-1 dependent chain; at MFMA dep-latency ~4x issue occupancy a
// serial chain caps each wave at ~25% -> 2 waves/SIMD -> the measured
// 52-54% MfmaUtil invariant. Alternating acc0/acc1 per MFMA gives dep
// distance 2 with ZERO extra accumulators (R1's 4-chain attempt died on
// the 256-reg cap, not on the idea). JIT B-reads (R8 proved pipelining
// null); rmp 8-bit index packing keeps arch VGPR ~124 + 128 AGPR <= 256.
__global__ __launch_bounds__(512, 2) void vq_main_kernel(
    const unsigned short* __restrict__ xh, const unsigned short* __restrict__ xl,
    const unsigned short* __restrict__ eh, const unsigned short* __restrict__ el,
    const float* __restrict__ e2h, unsigned long long* __restrict__ keys) {
  // [buf][half][code*256 + swizzled runs]; 128 KB total, dense (DMA-ok).
  // 16B-slot s of code row c holds run g = s ^ (c&31).
  __shared__ __attribute__((aligned(16))) unsigned short Bs[2][2][CHUNK_ * 256];

  const int tid = threadIdx.x;
  const int w = tid >> 6;       // wave 0..7
  const int lane = tid & 63;
  const int l = lane & 31;      // spatial index (code col / query row)
  const int hi = lane >> 5;     // k-group half

  const int qt = blockIdx.x >> 2;
  const int ksl = blockIdx.x & 3;
  const int q0 = qt * QTILE_;
  const int kbase = ksl * KSLICE_;
  const int qw = q0 + w * 32;

  // Persistent A fragments: 32 queries x 256 d, hi+lo.
  // A[m=lane&31][k=hi*8+j]; 128 regs, allocator places in AGPRs.
  bf16x8 ah[16], al[16];
  {
    const unsigned short* pa = xh + (size_t)(qw + l) * D_ + hi * 8;
    const unsigned short* pb = xl + (size_t)(qw + l) * D_ + hi * 8;
#pragma unroll
    for (int kc16 = 0; kc16 < 16; ++kc16) {
      ah[kc16] = *(const bf16x8*)(pa + kc16 * 16);
      al[kc16] = *(const bf16x8*)(pb + kc16 * 16);
    }
  }

  float rminv[16];
  unsigned rmp[4];  // 16 x 8-bit packed chunk-subtile codes (vc = ch*2+st)
#pragma unroll
  for (int r = 0; r < 16; ++r) rminv[r] = __builtin_inff();
#pragma unroll
  for (int i = 0; i < 4; ++i) rmp[i] = 0u;

  // Stage chunk ch (64 codes x hi/lo) into buf: wave w loads codes
  // [w*8, w*8+8). One instr = 64 lanes x 16B = 2 code rows, swizzled via
  // source address. 8 gl_lds per wave per chunk.
  auto stage = [&](int ch, int buf) {
    const int kc = kbase + ch * CHUNK_;
#pragma unroll
    for (int p = 0; p < 4; ++p) {
      const int c0 = w * 8 + p * 2;
      const int c = c0 + hi;
      const int g = l ^ (c & 31);
      const size_t srcoff = (size_t)(kc + c) * D_ + g * 8;
      gl_lds16(eh + srcoff, &Bs[buf][0][c0 * 256]);
      gl_lds16(el + srcoff, &Bs[buf][1][c0 * 256]);
    }
  };

  stage(0, 0);

#pragma unroll 1
  for (int ch = 0; ch < NCHUNK_; ++ch) {
    const int buf = ch & 1;
    __syncthreads();                    // drains DMA for chunk ch
    if (ch + 1 < NCHUNK_) stage(ch + 1, buf ^ 1);
    const int kc = kbase + ch * CHUNK_;
    const float e2v0 = e2h[kc + l];       // L2-hot
    const float e2v1 = e2h[kc + 32 + l];

    f32x16 acc0, acc1;
#pragma unroll
    for (int r = 0; r < 16; ++r) { acc0[r] = 0.f; acc1[r] = 0.f; }

    // Two independent accumulator chains, alternated per MFMA (dep dist 2).
#pragma unroll
    for (int ks = 0; ks < 16; ++ks) {
      const int pos = (((ks * 2 + hi) ^ l) * 8);
      bf16x8 b0h = *(const bf16x8*)&Bs[buf][0][l * 256 + pos];
      bf16x8 b0l = *(const bf16x8*)&Bs[buf][1][l * 256 + pos];
      bf16x8 b1h = *(const bf16x8*)&Bs[buf][0][(32 + l) * 256 + pos];
      bf16x8 b1l = *(const bf16x8*)&Bs[buf][1][(32 + l) * 256 + pos];
      acc0 = __builtin_amdgcn_mfma_f32_32x32x16_bf16(ah[ks], b0h, acc0, 0, 0, 0);
      acc1 = __builtin_amdgcn_mfma_f32_32x32x16_bf16(ah[ks], b1h, acc1, 0, 0, 0);
      acc0 = __builtin_amdgcn_mfma_f32_32x32x16_bf16(ah[ks], b0l, acc0, 0, 0, 0);
      acc1 = __builtin_amdgcn_mfma_f32_32x32x16_bf16(ah[ks], b1l, acc1, 0, 0, 0);
      acc0 = __builtin_amdgcn_mfma_f32_32x32x16_bf16(al[ks], b0h, acc0, 0, 0, 0);
      acc1 = __builtin_amdgcn_mfma_f32_32x32x16_bf16(al[ks], b1h, acc1, 0, 0, 0);
    }

    {  // retire subtile 0
      const unsigned vc = (unsigned)(ch * 2 + 0);
#pragma unroll
      for (int r = 0; r < 16; ++r) {
        float dv = e2v0 - acc0[r];
        bool better = dv < rminv[r];
        rminv[r] = better ? dv : rminv[r];
        const unsigned sh = (r & 3) * 8;
        unsigned np = (rmp[r >> 2] & ~(0xFFu << sh)) | (vc << sh);
        rmp[r >> 2] = better ? np : rmp[r >> 2];
      }
    }
    {  // retire subtile 1
      const unsigned vc = (unsigned)(ch * 2 + 1);
#pragma unroll
      for (int r = 0; r < 16; ++r) {
        float dv = e2v1 - acc1[r];
        bool better = dv < rminv[r];
        rminv[r] = better ? dv : rminv[r];
        const unsigned sh = (r & 3) * 8;
        unsigned np = (rmp[r >> 2] & ~(0xFFu << sh)) | (vc << sh);
        rmp[r >> 2] = better ? np : rmp[r >> 2];
      }
    }
  }

  // Reduce over the 32 code-columns within each half-wave, then cross-block
  // merge via packed (sortable-float<<32 | idx) u64 atomicMin.
#pragma unroll
  for (int r = 0; r < 16; ++r) {
    float bv = rminv[r];
    const unsigned sh = (r & 3) * 8;
    int bi = kbase + (int)((rmp[r >> 2] >> sh) & 0xFFu) * 32 + l;
#pragma unroll
    for (int xm = 1; xm <= 16; xm <<= 1) {
      float ov = __shfl_xor(bv, xm, 64);
      int oi = __shfl_xor(bi, xm, 64);
      if (ov < bv || (ov == bv && oi < bi)) { bv = ov; bi = oi; }
    }
    if (l == 0) {
      const int m = (r & 3) + 8 * (r >> 2) + 4 * hi;  // C/D row mapping (m74/m101)
      const int qq = qw + m;
      unsigned su = __float_as_uint(bv);
      su ^= (unsigned)(((int)su >> 31) | 0x80000000u);
      unsigned long long key = ((unsigned long long)su << 32) | (unsigned)bi;
      atomicMin(keys + qq, key);
    }
  }
}

// Decode: out[b][d][n] = e[code[b,n]][d].
// Tiled LDS-transpose gather: reads e rows in coalesced 128B slices,
// writes out in 128B-contiguous n-runs.
__global__ void decode_kernel(const unsigned long long* __restrict__ keys,
                              const float* __restrict__ e,
                              float* __restrict__ out) {
  __shared__ float tile[32][33];
  __shared__ int codes[32];
  int b = blockIdx.y;
  int n0 = blockIdx.x * 32;
  int tx = threadIdx.x, ty = threadIdx.y;  // (32, 8)
  if (ty == 0)
    codes[tx] = (int)(keys[(size_t)b * N_ + n0 + tx] & 0xFFFFFFFFull);
  __syncthreads();
#pragma unroll 1
  for (int d0 = 0; d0 < D_; d0 += 32) {
    // gather: row nl's 32-d slice, coalesced 128B per row
#pragma unroll
    for (int i = 0; i < 4; ++i) {
      int nl = ty + 8 * i;
      tile[nl][tx] = e[(size_t)codes[nl] * D_ + d0 + tx];
    }
    __syncthreads();
    // transposed write: 32 consecutive n per instruction
#pragma unroll
    for (int i = 0; i < 4; ++i) {
      int dl = ty + 8 * i;
      out[((size_t)b * D_ + d0 + dl) * N_ + n0 + tx] = tile[tx][dl];
    }
    __syncthreads();
  }
}

extern "C" void kernel_launch(void* const* d_in, const int* in_sizes, int n_in,
                              void* d_out, int out_size, void* d_ws, size_t ws_size,
                              hipStream_t stream) {
  const float* x = (const float*)d_in[0];
  const float* e = (const float*)d_in[1];
  float* out = (float*)d_out;

  // workspace layout (~24.2 MB)
  char* wksp = (char*)d_ws;
  unsigned short* xh = (unsigned short*)wksp;                   // 8 MB
  unsigned short* xl = xh + (size_t)Q_ * D_;                    // 8 MB
  unsigned short* eh = xl + (size_t)Q_ * D_;                    // 4 MB
  unsigned short* el = eh + (size_t)K_ * D_;                    // 4 MB
  float* e2h = (float*)(el + (size_t)K_ * D_);                  // 32 KB
  unsigned long long* keys = (unsigned long long*)(e2h + K_);   // 128 KB

  prep_x_kernel<<<dim3(N_ / 32, D_ / 32, B_), dim3(32, 8), 0, stream>>>(x, xh, xl);
  prep_e_kernel<<<K_, 256, 0, stream>>>(e, eh, el, e2h, keys);
  vq_main_kernel<<<(Q_ / QTILE_) * KSPLIT_, 512, 0, stream>>>(xh, xl, eh, el, e2h, keys);
  decode_kernel<<<dim3(N_ / 32, B_), dim3(32, 8), 0, stream>>>(keys, e, out);
}

// Round 10
// 247.729 us; speedup vs baseline: 1.0675x; 1.0675x over previous
//
#include <hip/hip_runtime.h>
#include <stdint.h>

#define B_ 4
#define D_ 256
#define N_ 4096
#define K_ 8192
#define Q_ (B_*N_)   // 16384 queries

#define KSPLIT_ 4            // K-split
#define KSLICE_ (K_/KSPLIT_) // 2048 codes per block
#define CHUNK_ 64            // codes per chunk (2 x 32-code MFMA sub-tiles)
#define NCHUNK_ (KSLICE_/CHUNK_) // 32 chunks
#define QTILE_ 256           // queries per block (8 waves x 32)

typedef __attribute__((ext_vector_type(8))) short bf16x8;
typedef __attribute__((ext_vector_type(16))) float f32x16;
typedef __attribute__((ext_vector_type(4))) unsigned short us4;

__device__ __forceinline__ unsigned short f32_to_bf16(float f) {
  unsigned u = __float_as_uint(f);
  unsigned r = 0x7FFFu + ((u >> 16) & 1u);
  return (unsigned short)((u + r) >> 16);
}
__device__ __forceinline__ float bf16_to_f32(unsigned short h) {
  return __uint_as_float(((unsigned)h) << 16);
}

// async global->LDS, 16B per lane; LDS dest is wave-uniform base + lane*16
__device__ __forceinline__ void gl_lds16(const void* g, void* l) {
  __builtin_amdgcn_global_load_lds(
      (const __attribute__((address_space(1))) unsigned int*)g,
      (__attribute__((address_space(3))) unsigned int*)l, 16, 0, 0);
}

// Fused prep (R10): one launch replaces prep_x + prep_e.
// Blocks [0,256): x-role — transpose a 64n x 256d slab of x[b] into
//   xh/xl [q][d] bf16 hi/lo. float4 loads (128B/8-lane run), LDS transpose,
//   then per-q WHOLE-WAVE short4 stores (512 B contiguous per instr) —
//   replaces the old scalar u16 stores (64 B/instr, G13 violation).
// Blocks [256,1280): e-role — wave-per-code: one float4 load (1 KB/wave),
//   short4 eh/el stores, 6-shfl butterfly for 0.5*||e||^2, keys init.
__global__ __launch_bounds__(512) void prep_kernel(
    const float* __restrict__ x, const float* __restrict__ e,
    unsigned short* __restrict__ xh, unsigned short* __restrict__ xl,
    unsigned short* __restrict__ eh, unsigned short* __restrict__ el,
    float* __restrict__ e2h, unsigned long long* __restrict__ keys) {
  __shared__ float tile[64][260];  // pad 260: b128-aligned rows, low conflicts
  const int t = threadIdx.x;
  const int w = t >> 6;
  const int lam = t & 63;

  if (blockIdx.x < 256) {
    const int b = blockIdx.x >> 6;
    const int n0 = (blockIdx.x & 63) << 6;
    // phase 1: load 64d x 64n per pass, 4 passes; stage transposed tile[n][d]
#pragma unroll
    for (int p = 0; p < 4; ++p) {
      const int d = p * 64 + (t >> 3);
      const int f4 = t & 7;
      const float* src = x + (size_t)(b * D_ + d) * N_ + n0;
      float4 v1 = *(const float4*)(src + f4 * 4);
      float4 v2 = *(const float4*)(src + 32 + f4 * 4);
      tile[f4 * 4 + 0][d] = v1.x; tile[f4 * 4 + 1][d] = v1.y;
      tile[f4 * 4 + 2][d] = v1.z; tile[f4 * 4 + 3][d] = v1.w;
      tile[32 + f4 * 4 + 0][d] = v2.x; tile[32 + f4 * 4 + 1][d] = v2.y;
      tile[32 + f4 * 4 + 2][d] = v2.z; tile[32 + f4 * 4 + 3][d] = v2.w;
    }
    __syncthreads();
    // phase 2: wave w writes q rows w*8..w*8+7; lane lam covers d=4lam..+3
#pragma unroll
    for (int i = 0; i < 8; ++i) {
      const int q = w * 8 + i;
      float4 v = *(const float4*)&tile[q][lam * 4];
      unsigned short h0 = f32_to_bf16(v.x), h1 = f32_to_bf16(v.y);
      unsigned short h2 = f32_to_bf16(v.z), h3 = f32_to_bf16(v.w);
      us4 hv = {h0, h1, h2, h3};
      us4 lv = {f32_to_bf16(v.x - bf16_to_f32(h0)),
                f32_to_bf16(v.y - bf16_to_f32(h1)),
                f32_to_bf16(v.z - bf16_to_f32(h2)),
                f32_to_bf16(v.w - bf16_to_f32(h3))};
      const size_t qg = (size_t)b * N_ + n0 + q;
      *(us4*)(xh + qg * D_ + lam * 4) = hv;
      *(us4*)(xl + qg * D_ + lam * 4) = lv;
    }
  } else {
    const int k0 = ((int)blockIdx.x - 256) * 8;
    const int k = k0 + w;
    float4 v = *(const float4*)(e + (size_t)k * D_ + lam * 4);
    unsigned short h0 = f32_to_bf16(v.x), h1 = f32_to_bf16(v.y);
    unsigned short h2 = f32_to_bf16(v.z), h3 = f32_to_bf16(v.w);
    us4 hv = {h0, h1, h2, h3};
    us4 lv = {f32_to_bf16(v.x - bf16_to_f32(h0)),
              f32_to_bf16(v.y - bf16_to_f32(h1)),
              f32_to_bf16(v.z - bf16_to_f32(h2)),
              f32_to_bf16(v.w - bf16_to_f32(h3))};
    *(us4*)(eh + (size_t)k * D_ + lam * 4) = hv;
    *(us4*)(el + (size_t)k * D_ + lam * 4) = lv;
    float sq = v.x * v.x + v.y * v.y + v.z * v.z + v.w * v.w;
#pragma unroll
    for (int xm = 1; xm <= 32; xm <<= 1) sq += __shfl_xor(sq, xm, 64);
    if (lam == 0) e2h[k] = 0.5f * sq;
    if (t < 16) keys[(size_t)k0 * 2 + t] = ~0ull;
  }
}

// Main R10 == R8 verbatim (best measured: 180.2 us, MfmaUtil 54%).
// R0-R9 established: vq_main is pinned at ~52-54% MfmaUtil under every
// structural variation (barrier domains, acc chains, vmcnt counting,
// M-ratio, chunk size, read pipelining, MFMA interleave). 53% is near the
// practical LDS-fed MFMA schedule ceiling on this chip (m201: 62%,
// hipBLASLt: 58%). Do not touch.
__global__ __launch_bounds__(512, 2) void vq_main_kernel(
    const unsigned short* __restrict__ xh, const unsigned short* __restrict__ xl,
    const unsigned short* __restrict__ eh, const unsigned short* __restrict__ el,
    const float* __restrict__ e2h, unsigned long long* __restrict__ keys) {
  // [buf][half][code*256 + swizzled runs]; 128 KB total, dense (DMA-ok).
  // 16B-slot s of code row c holds run g = s ^ (c&31).
  __shared__ __attribute__((aligned(16))) unsigned short Bs[2][2][CHUNK_ * 256];

  const int tid = threadIdx.x;
  const int w = tid >> 6;       // wave 0..7
  const int lane = tid & 63;
  const int l = lane & 31;      // spatial index (code col / query row)
  const int hi = lane >> 5;     // k-group half

  const int qt = blockIdx.x >> 2;
  const int ksl = blockIdx.x & 3;
  const int q0 = qt * QTILE_;
  const int kbase = ksl * KSLICE_;
  const int qw = q0 + w * 32;

  // Persistent A fragments: 32 queries x 256 d, hi+lo.
  // A[m=lane&31][k=hi*8+j]; 128 regs, allocator places in AGPRs.
  bf16x8 ah[16], al[16];
  {
    const unsigned short* pa = xh + (size_t)(qw + l) * D_ + hi * 8;
    const unsigned short* pb = xl + (size_t)(qw + l) * D_ + hi * 8;
#pragma unroll
    for (int kc16 = 0; kc16 < 16; ++kc16) {
      ah[kc16] = *(const bf16x8*)(pa + kc16 * 16);
      al[kc16] = *(const bf16x8*)(pb + kc16 * 16);
    }
  }

  float rminv[16];
  unsigned rmp[4];  // 16 x 8-bit packed chunk-subtile codes (vc = ch*2+st)
#pragma unroll
  for (int r = 0; r < 16; ++r) rminv[r] = __builtin_inff();
#pragma unroll
  for (int i = 0; i < 4; ++i) rmp[i] = 0u;

  // Stage chunk ch (64 codes x hi/lo) into buf: wave w loads codes
  // [w*8, w*8+8). One instr = 64 lanes x 16B = 2 code rows, swizzled via
  // source address. 8 gl_lds per wave per chunk.
  auto stage = [&](int ch, int buf) {
    const int kc = kbase + ch * CHUNK_;
#pragma unroll
    for (int p = 0; p < 4; ++p) {
      const int c0 = w * 8 + p * 2;
      const int c = c0 + hi;
      const int g = l ^ (c & 31);
      const size_t srcoff = (size_t)(kc + c) * D_ + g * 8;
      gl_lds16(eh + srcoff, &Bs[buf][0][c0 * 256]);
      gl_lds16(el + srcoff, &Bs[buf][1][c0 * 256]);
    }
  };

  stage(0, 0);

#pragma unroll 1
  for (int ch = 0; ch < NCHUNK_; ++ch) {
    const int buf = ch & 1;
    __syncthreads();                    // drains DMA for chunk ch
    if (ch + 1 < NCHUNK_) stage(ch + 1, buf ^ 1);
    const int kc = kbase + ch * CHUNK_;
    const float e2v0 = e2h[kc + l];       // in flight under first iters
    const float e2v1 = e2h[kc + 32 + l];

    const unsigned short* bh_base = &Bs[buf][0][0];
    const unsigned short* bl_base = &Bs[buf][1][0];
    // read for fused iter kk: subtile st=kk>>4 (row 32*st+l), ks=kk&15
#define RD(base, kk) \
    (*(const bf16x8*)&(base)[(((kk) >> 4) * 32 + l) * 256 + \
                             (((((kk) & 15) * 2 + hi) ^ l) * 8)])

    f32x16 acc0, acc1;
#pragma unroll
    for (int r = 0; r < 16; ++r) { acc0[r] = 0.f; acc1[r] = 0.f; }

    // depth-2 software pipeline: reads for kk+2 issue before MFMAs of kk
    bf16x8 cbh = RD(bh_base, 0), cbl = RD(bl_base, 0);
    bf16x8 nbh = RD(bh_base, 1), nbl = RD(bl_base, 1);
#pragma unroll
    for (int kk = 0; kk < 32; ++kk) {
      const bf16x8 ubh = cbh, ubl = cbl;
      cbh = nbh; cbl = nbl;
      if (kk + 2 < 32) { nbh = RD(bh_base, kk + 2); nbl = RD(bl_base, kk + 2); }
      const int ks = kk & 15;
      if (kk < 16) {
        acc0 = __builtin_amdgcn_mfma_f32_32x32x16_bf16(ah[ks], ubh, acc0, 0, 0, 0);
        acc0 = __builtin_amdgcn_mfma_f32_32x32x16_bf16(ah[ks], ubl, acc0, 0, 0, 0);
        acc0 = __builtin_amdgcn_mfma_f32_32x32x16_bf16(al[ks], ubh, acc0, 0, 0, 0);
      } else {
        acc1 = __builtin_amdgcn_mfma_f32_32x32x16_bf16(ah[ks], ubh, acc1, 0, 0, 0);
        acc1 = __builtin_amdgcn_mfma_f32_32x32x16_bf16(ah[ks], ubl, acc1, 0, 0, 0);
        acc1 = __builtin_amdgcn_mfma_f32_32x32x16_bf16(al[ks], ubh, acc1, 0, 0, 0);
      }
      if (kk == 15) {  // retire subtile 0 (frees acc0 pressure early)
        const unsigned vc = (unsigned)(ch * 2 + 0);
#pragma unroll
        for (int r = 0; r < 16; ++r) {
          float dv = e2v0 - acc0[r];
          bool better = dv < rminv[r];
          rminv[r] = better ? dv : rminv[r];
          const unsigned sh = (r & 3) * 8;
          unsigned np = (rmp[r >> 2] & ~(0xFFu << sh)) | (vc << sh);
          rmp[r >> 2] = better ? np : rmp[r >> 2];
        }
      }
    }
#undef RD
    {  // retire subtile 1
      const unsigned vc = (unsigned)(ch * 2 + 1);
#pragma unroll
      for (int r = 0; r < 16; ++r) {
        float dv = e2v1 - acc1[r];
        bool better = dv < rminv[r];
        rminv[r] = better ? dv : rminv[r];
        const unsigned sh = (r & 3) * 8;
        unsigned np = (rmp[r >> 2] & ~(0xFFu << sh)) | (vc << sh);
        rmp[r >> 2] = better ? np : rmp[r >> 2];
      }
    }
  }

  // Reduce over the 32 code-columns within each half-wave, then cross-block
  // merge via packed (sortable-float<<32 | idx) u64 atomicMin.
#pragma unroll
  for (int r = 0; r < 16; ++r) {
    float bv = rminv[r];
    const unsigned sh = (r & 3) * 8;
    int bi = kbase + (int)((rmp[r >> 2] >> sh) & 0xFFu) * 32 + l;
#pragma unroll
    for (int xm = 1; xm <= 16; xm <<= 1) {
      float ov = __shfl_xor(bv, xm, 64);
      int oi = __shfl_xor(bi, xm, 64);
      if (ov < bv || (ov == bv && oi < bi)) { bv = ov; bi = oi; }
    }
    if (l == 0) {
      const int m = (r & 3) + 8 * (r >> 2) + 4 * hi;  // C/D row mapping (m74/m101)
      const int qq = qw + m;
      unsigned su = __float_as_uint(bv);
      su ^= (unsigned)(((int)su >> 31) | 0x80000000u);
      unsigned long long key = ((unsigned long long)su << 32) | (unsigned)bi;
      atomicMin(keys + qq, key);
    }
  }
}

// Decode v2 (R10): out[b][d][n] = e[code[b,n]][d].
// Stage 32 full e-rows via float4 (1 KB per wave-instr, L3-hot), 2 barriers
// total (was 16), float4 output stores (128 B runs). Block 256 = 4 waves.
__global__ __launch_bounds__(256) void decode_kernel(
    const unsigned long long* __restrict__ keys,
    const float* __restrict__ e, float* __restrict__ out) {
  __shared__ float tile[32][260];
  __shared__ int codes[32];
  const int t = threadIdx.x;
  const int b = blockIdx.y;
  const int n0 = blockIdx.x * 32;
  const int w = t >> 6, lam = t & 63;
  if (t < 32)
    codes[t] = (int)(keys[(size_t)b * N_ + n0 + t] & 0xFFFFFFFFull);
  __syncthreads();
  // stage: wave w loads rows w*8..w*8+7, coalesced 1 KB per row
#pragma unroll
  for (int i = 0; i < 8; ++i) {
    const int row = w * 8 + i;
    float4 ev = *(const float4*)(e + (size_t)codes[row] * D_ + lam * 4);
    *(float4*)&tile[row][lam * 4] = ev;
  }
  __syncthreads();
  // write: per iter, 32 d-rows x 32 n; lane covers 4 consecutive n (16 B)
#pragma unroll
  for (int iter = 0; iter < 8; ++iter) {
    const int d = iter * 32 + (t >> 3);
    const int nc = (t & 7) * 4;
    float4 ov = {tile[nc][d], tile[nc + 1][d], tile[nc + 2][d], tile[nc + 3][d]};
    *(float4*)(out + (size_t)(b * D_ + d) * N_ + n0 + nc) = ov;
  }
}

extern "C" void kernel_launch(void* const* d_in, const int* in_sizes, int n_in,
                              void* d_out, int out_size, void* d_ws, size_t ws_size,
                              hipStream_t stream) {
  const float* x = (const float*)d_in[0];
  const float* e = (const float*)d_in[1];
  float* out = (float*)d_out;

  // workspace layout (~24.2 MB)
  char* wksp = (char*)d_ws;
  unsigned short* xh = (unsigned short*)wksp;                   // 8 MB
  unsigned short* xl = xh + (size_t)Q_ * D_;                    // 8 MB
  unsigned short* eh = xl + (size_t)Q_ * D_;                    // 4 MB
  unsigned short* el = eh + (size_t)K_ * D_;                    // 4 MB
  float* e2h = (float*)(el + (size_t)K_ * D_);                  // 32 KB
  unsigned long long* keys = (unsigned long long*)(e2h + K_);   // 128 KB

  prep_kernel<<<1280, 512, 0, stream>>>(x, e, xh, xl, eh, el, e2h, keys);
  vq_main_kernel<<<(Q_ / QTILE_) * KSPLIT_, 512, 0, stream>>>(xh, xl, eh, el, e2h, keys);
  decode_kernel<<<dim3(N_ / 32, B_), 256, 0, stream>>>(keys, e, out);
}